// Round 1
// baseline (73.784 us; speedup 1.0000x reference)
//
#include <hip/hip_runtime.h>

#define IN_DIM  4096
#define OUT_DIM 8192
#define BATCH   4096
#define ROWS    4          // x rows staged in LDS per block (64 KB)
#define TPB     256
#define COLS_PER_THREAD 4  // float4 output stores

// difflogic op-coefficient table: op_i(a,b) = T[i][0] + T[i][1]*a + T[i][2]*b + T[i][3]*ab
__device__ __constant__ float c_T[16][4] = {
    {0.f,  0.f,  0.f,  0.f},
    {0.f,  0.f,  0.f,  1.f},
    {0.f,  1.f,  0.f, -1.f},
    {0.f,  1.f,  0.f,  0.f},
    {0.f,  0.f,  1.f, -1.f},
    {0.f,  0.f,  1.f,  0.f},
    {0.f,  1.f,  1.f, -2.f},
    {0.f,  1.f,  1.f, -1.f},
    {1.f, -1.f, -1.f,  1.f},
    {1.f, -1.f, -1.f,  2.f},
    {1.f,  0.f, -1.f,  0.f},
    {1.f,  0.f, -1.f,  1.f},
    {1.f, -1.f,  0.f,  0.f},
    {1.f, -1.f,  0.f,  1.f},
    {1.f,  0.f,  0.f, -1.f},
    {1.f,  0.f,  0.f,  0.f},
};

// coeff[j] = softmax(weight[j,:]) @ T   -> float4 per output column
__global__ __launch_bounds__(256) void coeff_kernel(const float* __restrict__ w,
                                                    float4* __restrict__ coeff) {
    int j = blockIdx.x * blockDim.x + threadIdx.x;
    if (j >= OUT_DIM) return;
    const float4* wp = (const float4*)(w + (size_t)j * 16);
    float4 a0 = wp[0], a1 = wp[1], a2 = wp[2], a3 = wp[3];
    float v[16] = {a0.x, a0.y, a0.z, a0.w, a1.x, a1.y, a1.z, a1.w,
                   a2.x, a2.y, a2.z, a2.w, a3.x, a3.y, a3.z, a3.w};
    float m = v[0];
#pragma unroll
    for (int i = 1; i < 16; ++i) m = fmaxf(m, v[i]);
    float s = 0.f, c0 = 0.f, c1 = 0.f, c2 = 0.f, c3 = 0.f;
#pragma unroll
    for (int i = 0; i < 16; ++i) {
        float e = __expf(v[i] - m);
        s += e;
        c0 += e * c_T[i][0];
        c1 += e * c_T[i][1];
        c2 += e * c_T[i][2];
        c3 += e * c_T[i][3];
    }
    float inv = 1.f / s;
    coeff[j] = make_float4(c0 * inv, c1 * inv, c2 * inv, c3 * inv);
}

// Main kernel: each block stages ROWS full x-rows in LDS (coalesced, read from
// HBM exactly once), then computes all OUT_DIM columns for those rows.
// Each thread owns 4 consecutive columns -> float4 coalesced stores.
__global__ __launch_bounds__(TPB) void logic_main(const float* __restrict__ x,
                                                  const int* __restrict__ idx,
                                                  const float4* __restrict__ coeff,
                                                  float* __restrict__ out) {
    __shared__ float xs[ROWS * IN_DIM];  // 64 KB

    const int row0 = blockIdx.x * ROWS;

    // --- stage ROWS rows of x into LDS (float4 coalesced) ---
    {
        const float4* src = (const float4*)(x + (size_t)row0 * IN_DIM);
        float4* dst = (float4*)xs;
        const int n4 = ROWS * IN_DIM / 4;  // 4096
#pragma unroll
        for (int t = threadIdx.x; t < n4; t += TPB) dst[t] = src[t];
    }
    __syncthreads();

    // --- sweep all columns, 4 per thread per chunk ---
    const int jbase = threadIdx.x * COLS_PER_THREAD;
#pragma unroll 1
    for (int jb = 0; jb < OUT_DIM; jb += TPB * COLS_PER_THREAD) {
        const int j = jb + jbase;
        const int4 i0 = *(const int4*)(idx + j);            // idx0[j..j+3]
        const int4 i1 = *(const int4*)(idx + OUT_DIM + j);  // idx1[j..j+3]
        const float4 cf0 = coeff[j + 0];
        const float4 cf1 = coeff[j + 1];
        const float4 cf2 = coeff[j + 2];
        const float4 cf3 = coeff[j + 3];
#pragma unroll
        for (int r = 0; r < ROWS; ++r) {
            const float* xr = xs + r * IN_DIM;
            float a, b;
            float4 o;
            a = xr[i0.x]; b = xr[i1.x];
            o.x = cf0.x + cf0.y * a + cf0.z * b + cf0.w * (a * b);
            a = xr[i0.y]; b = xr[i1.y];
            o.y = cf1.x + cf1.y * a + cf1.z * b + cf1.w * (a * b);
            a = xr[i0.z]; b = xr[i1.z];
            o.z = cf2.x + cf2.y * a + cf2.z * b + cf2.w * (a * b);
            a = xr[i0.w]; b = xr[i1.w];
            o.w = cf3.x + cf3.y * a + cf3.z * b + cf3.w * (a * b);
            *(float4*)(out + (size_t)(row0 + r) * OUT_DIM + j) = o;
        }
    }
}

extern "C" void kernel_launch(void* const* d_in, const int* in_sizes, int n_in,
                              void* d_out, int out_size, void* d_ws, size_t ws_size,
                              hipStream_t stream) {
    const float* x   = (const float*)d_in[0];
    const int*   idx = (const int*)d_in[1];     // (2, OUT_DIM) int32
    const float* w   = (const float*)d_in[2];   // (OUT_DIM, 16)
    float* out = (float*)d_out;
    float4* coeff = (float4*)d_ws;              // OUT_DIM float4 = 128 KB scratch

    coeff_kernel<<<OUT_DIM / 256, 256, 0, stream>>>(w, coeff);
    logic_main<<<BATCH / ROWS, TPB, 0, stream>>>(x, idx, coeff, out);
}

// Round 2
// 71.465 us; speedup vs baseline: 1.0324x; 1.0324x over previous
//
#include <hip/hip_runtime.h>

#define IN_DIM  4096
#define OUT_DIM 8192
#define BATCH   4096
#define ROWS    2          // x rows staged in LDS per block (32 KB)
#define TPB     512        // 8 waves/block; 4 blocks/CU -> 32 waves (100% occ)
#define COLS_PER_THREAD 4  // float4 output stores

// difflogic op-coefficient table: op_i(a,b) = T[i][0] + T[i][1]*a + T[i][2]*b + T[i][3]*ab
__device__ __constant__ float c_T[16][4] = {
    {0.f,  0.f,  0.f,  0.f},
    {0.f,  0.f,  0.f,  1.f},
    {0.f,  1.f,  0.f, -1.f},
    {0.f,  1.f,  0.f,  0.f},
    {0.f,  0.f,  1.f, -1.f},
    {0.f,  0.f,  1.f,  0.f},
    {0.f,  1.f,  1.f, -2.f},
    {0.f,  1.f,  1.f, -1.f},
    {1.f, -1.f, -1.f,  1.f},
    {1.f, -1.f, -1.f,  2.f},
    {1.f,  0.f, -1.f,  0.f},
    {1.f,  0.f, -1.f,  1.f},
    {1.f, -1.f,  0.f,  0.f},
    {1.f, -1.f,  0.f,  1.f},
    {1.f,  0.f,  0.f, -1.f},
    {1.f,  0.f,  0.f,  0.f},
};

// coeff[j] = softmax(weight[j,:]) @ T   -> float4 per output column
__global__ __launch_bounds__(256) void coeff_kernel(const float* __restrict__ w,
                                                    float4* __restrict__ coeff) {
    int j = blockIdx.x * blockDim.x + threadIdx.x;
    if (j >= OUT_DIM) return;
    const float4* wp = (const float4*)(w + (size_t)j * 16);
    float4 a0 = wp[0], a1 = wp[1], a2 = wp[2], a3 = wp[3];
    float v[16] = {a0.x, a0.y, a0.z, a0.w, a1.x, a1.y, a1.z, a1.w,
                   a2.x, a2.y, a2.z, a2.w, a3.x, a3.y, a3.z, a3.w};
    float m = v[0];
#pragma unroll
    for (int i = 1; i < 16; ++i) m = fmaxf(m, v[i]);
    float s = 0.f, c0 = 0.f, c1 = 0.f, c2 = 0.f, c3 = 0.f;
#pragma unroll
    for (int i = 0; i < 16; ++i) {
        float e = __expf(v[i] - m);
        s += e;
        c0 += e * c_T[i][0];
        c1 += e * c_T[i][1];
        c2 += e * c_T[i][2];
        c3 += e * c_T[i][3];
    }
    float inv = 1.f / s;
    coeff[j] = make_float4(c0 * inv, c1 * inv, c2 * inv, c3 * inv);
}

// Main kernel: each block stages ROWS full x-rows in LDS (coalesced, read from
// HBM exactly once), then computes all OUT_DIM columns for those rows.
// Each thread owns 4 consecutive columns -> float4 coalesced stores.
// ROWS=2/TPB=512: 32 KB LDS -> 4 blocks/CU (wave-slot bound) = 32 waves/CU.
__global__ __launch_bounds__(TPB) void logic_main(const float* __restrict__ x,
                                                  const int* __restrict__ idx,
                                                  const float4* __restrict__ coeff,
                                                  float* __restrict__ out) {
    __shared__ float xs[ROWS * IN_DIM];  // 32 KB

    const int row0 = blockIdx.x * ROWS;

    // --- stage ROWS rows of x into LDS (float4 coalesced) ---
    {
        const float4* src = (const float4*)(x + (size_t)row0 * IN_DIM);
        float4* dst = (float4*)xs;
        const int n4 = ROWS * IN_DIM / 4;  // 2048
#pragma unroll
        for (int t = threadIdx.x; t < n4; t += TPB) dst[t] = src[t];
    }
    __syncthreads();

    // --- sweep all columns, 4 per thread per chunk (4 chunks) ---
    const int jbase = threadIdx.x * COLS_PER_THREAD;
#pragma unroll 1
    for (int jb = 0; jb < OUT_DIM; jb += TPB * COLS_PER_THREAD) {
        const int j = jb + jbase;
        const int4 i0 = *(const int4*)(idx + j);            // idx0[j..j+3]
        const int4 i1 = *(const int4*)(idx + OUT_DIM + j);  // idx1[j..j+3]
        const float4 cf0 = coeff[j + 0];
        const float4 cf1 = coeff[j + 1];
        const float4 cf2 = coeff[j + 2];
        const float4 cf3 = coeff[j + 3];
#pragma unroll
        for (int r = 0; r < ROWS; ++r) {
            const float* xr = xs + r * IN_DIM;
            float a, b;
            float4 o;
            a = xr[i0.x]; b = xr[i1.x];
            o.x = cf0.x + cf0.y * a + cf0.z * b + cf0.w * (a * b);
            a = xr[i0.y]; b = xr[i1.y];
            o.y = cf1.x + cf1.y * a + cf1.z * b + cf1.w * (a * b);
            a = xr[i0.z]; b = xr[i1.z];
            o.z = cf2.x + cf2.y * a + cf2.z * b + cf2.w * (a * b);
            a = xr[i0.w]; b = xr[i1.w];
            o.w = cf3.x + cf3.y * a + cf3.z * b + cf3.w * (a * b);
            *(float4*)(out + (size_t)(row0 + r) * OUT_DIM + j) = o;
        }
    }
}

extern "C" void kernel_launch(void* const* d_in, const int* in_sizes, int n_in,
                              void* d_out, int out_size, void* d_ws, size_t ws_size,
                              hipStream_t stream) {
    const float* x   = (const float*)d_in[0];
    const int*   idx = (const int*)d_in[1];     // (2, OUT_DIM) int32
    const float* w   = (const float*)d_in[2];   // (OUT_DIM, 16)
    float* out = (float*)d_out;
    float4* coeff = (float4*)d_ws;              // OUT_DIM float4 = 128 KB scratch

    coeff_kernel<<<OUT_DIM / 256, 256, 0, stream>>>(w, coeff);
    logic_main<<<BATCH / ROWS, TPB, 0, stream>>>(x, idx, coeff, out);
}

// Round 4
// 42.318 us; speedup vs baseline: 1.7436x; 1.6888x over previous
//
#include <hip/hip_runtime.h>

#define IN_DIM  4096
#define OUT_DIM 8192
#define BATCH   4096
#define ROWS    2          // rows staged per block, interleaved per-column
#define TPB     512
#define CPT     4          // columns per thread per chunk
#define NCHUNK  (OUT_DIM / (TPB * CPT))   // 4

typedef float f32x4 __attribute__((ext_vector_type(4)));  // native vec for nontemporal store

// difflogic op-coefficient table: op_i(a,b) = T[i][0] + T[i][1]*a + T[i][2]*b + T[i][3]*ab
__device__ __constant__ float c_T[16][4] = {
    {0.f,  0.f,  0.f,  0.f},
    {0.f,  0.f,  0.f,  1.f},
    {0.f,  1.f,  0.f, -1.f},
    {0.f,  1.f,  0.f,  0.f},
    {0.f,  0.f,  1.f, -1.f},
    {0.f,  0.f,  1.f,  0.f},
    {0.f,  1.f,  1.f, -2.f},
    {0.f,  1.f,  1.f, -1.f},
    {1.f, -1.f, -1.f,  1.f},
    {1.f, -1.f, -1.f,  2.f},
    {1.f,  0.f, -1.f,  0.f},
    {1.f,  0.f, -1.f,  1.f},
    {1.f, -1.f,  0.f,  0.f},
    {1.f, -1.f,  0.f,  1.f},
    {1.f,  0.f,  0.f, -1.f},
    {1.f,  0.f,  0.f,  0.f},
};

__global__ __launch_bounds__(256) void coeff_kernel(const float* __restrict__ w,
                                                    float4* __restrict__ coeff) {
    int j = blockIdx.x * blockDim.x + threadIdx.x;
    if (j >= OUT_DIM) return;
    const float4* wp = (const float4*)(w + (size_t)j * 16);
    float4 a0 = wp[0], a1 = wp[1], a2 = wp[2], a3 = wp[3];
    float v[16] = {a0.x, a0.y, a0.z, a0.w, a1.x, a1.y, a1.z, a1.w,
                   a2.x, a2.y, a2.z, a2.w, a3.x, a3.y, a3.z, a3.w};
    float m = v[0];
#pragma unroll
    for (int i = 1; i < 16; ++i) m = fmaxf(m, v[i]);
    float s = 0.f, c0 = 0.f, c1 = 0.f, c2 = 0.f, c3 = 0.f;
#pragma unroll
    for (int i = 0; i < 16; ++i) {
        float e = __expf(v[i] - m);
        s += e;
        c0 += e * c_T[i][0];
        c1 += e * c_T[i][1];
        c2 += e * c_T[i][2];
        c3 += e * c_T[i][3];
    }
    float inv = 1.f / s;
    coeff[j] = make_float4(c0 * inv, c1 * inv, c2 * inv, c3 * inv);
}

// Each block: 2 rows of x staged in LDS INTERLEAVED per column
// (xs[2c]=row0[c], xs[2c+1]=row1[c]) so one ds_read_b64 serves both rows.
// Chunk loop is fully unrolled with a register double-buffer prefetch of the
// next chunk's idx/coeff, and chunk 0's loads issue before the staging barrier.
__global__ __launch_bounds__(TPB) void logic_main(const float* __restrict__ x,
                                                  const int* __restrict__ idx,
                                                  const float4* __restrict__ coeff,
                                                  float* __restrict__ out) {
    __shared__ float xs[ROWS * IN_DIM];  // 32 KB, interleaved {r0,r1} pairs

    const int row0 = blockIdx.x * ROWS;
    const int jbase = threadIdx.x * CPT;

    // --- prefetch chunk 0's idx/coeff (overlaps with staging) ---
    int4   i0 = *(const int4*)(idx + jbase);
    int4   i1 = *(const int4*)(idx + OUT_DIM + jbase);
    float4 c0 = coeff[jbase + 0];
    float4 c1 = coeff[jbase + 1];
    float4 c2 = coeff[jbase + 2];
    float4 c3 = coeff[jbase + 3];

    // --- stage 2 rows, transposing to interleaved layout ---
    {
        const float4* r0 = (const float4*)(x + (size_t)row0 * IN_DIM);
        const float4* r1 = r0 + IN_DIM / 4;
#pragma unroll
        for (int t = threadIdx.x; t < IN_DIM / 4; t += TPB) {  // 2 iters
            float4 a = r0[t], b = r1[t];
            float4* d = (float4*)(xs + 8 * t);   // stride 32 B -> 2-way (free)
            d[0] = make_float4(a.x, b.x, a.y, b.y);
            d[1] = make_float4(a.z, b.z, a.w, b.w);
        }
    }
    __syncthreads();

#pragma unroll
    for (int chunk = 0; chunk < NCHUNK; ++chunk) {
        const int j = chunk * (TPB * CPT) + jbase;
        // consume current regs
        const int4   I0 = i0, I1 = i1;
        const float4 C0 = c0, C1 = c1, C2 = c2, C3 = c3;
        // prefetch next chunk
        if (chunk < NCHUNK - 1) {
            const int jn = j + TPB * CPT;
            i0 = *(const int4*)(idx + jn);
            i1 = *(const int4*)(idx + OUT_DIM + jn);
            c0 = coeff[jn + 0];
            c1 = coeff[jn + 1];
            c2 = coeff[jn + 2];
            c3 = coeff[jn + 3];
        }
        // gathers: one b64 per (col, a/b) serves both rows
        const float2 a0 = *(const float2*)(xs + 2 * I0.x);
        const float2 b0 = *(const float2*)(xs + 2 * I1.x);
        const float2 a1v = *(const float2*)(xs + 2 * I0.y);
        const float2 b1v = *(const float2*)(xs + 2 * I1.y);
        const float2 a2v = *(const float2*)(xs + 2 * I0.z);
        const float2 b2v = *(const float2*)(xs + 2 * I1.z);
        const float2 a3v = *(const float2*)(xs + 2 * I0.w);
        const float2 b3v = *(const float2*)(xs + 2 * I1.w);

        f32x4 o0, o1;  // row0, row1 outputs (4 cols each)
        o0.x = C0.x + C0.y * a0.x  + C0.z * b0.x  + C0.w * (a0.x  * b0.x);
        o1.x = C0.x + C0.y * a0.y  + C0.z * b0.y  + C0.w * (a0.y  * b0.y);
        o0.y = C1.x + C1.y * a1v.x + C1.z * b1v.x + C1.w * (a1v.x * b1v.x);
        o1.y = C1.x + C1.y * a1v.y + C1.z * b1v.y + C1.w * (a1v.y * b1v.y);
        o0.z = C2.x + C2.y * a2v.x + C2.z * b2v.x + C2.w * (a2v.x * b2v.x);
        o1.z = C2.x + C2.y * a2v.y + C2.z * b2v.y + C2.w * (a2v.y * b2v.y);
        o0.w = C3.x + C3.y * a3v.x + C3.z * b3v.x + C3.w * (a3v.x * b3v.x);
        o1.w = C3.x + C3.y * a3v.y + C3.z * b3v.y + C3.w * (a3v.y * b3v.y);

        __builtin_nontemporal_store(o0, (f32x4*)(out + (size_t)row0 * OUT_DIM + j));
        __builtin_nontemporal_store(o1, (f32x4*)(out + (size_t)(row0 + 1) * OUT_DIM + j));
    }
}

extern "C" void kernel_launch(void* const* d_in, const int* in_sizes, int n_in,
                              void* d_out, int out_size, void* d_ws, size_t ws_size,
                              hipStream_t stream) {
    const float* x   = (const float*)d_in[0];
    const int*   idx = (const int*)d_in[1];     // (2, OUT_DIM) int32
    const float* w   = (const float*)d_in[2];   // (OUT_DIM, 16)
    float* out = (float*)d_out;
    float4* coeff = (float4*)d_ws;              // OUT_DIM float4 = 128 KB scratch

    coeff_kernel<<<OUT_DIM / 256, 256, 0, stream>>>(w, coeff);
    logic_main<<<BATCH / ROWS, TPB, 0, stream>>>(x, idx, coeff, out);
}

// Round 5
// 39.740 us; speedup vs baseline: 1.8567x; 1.0649x over previous
//
#include <hip/hip_runtime.h>

#define IN_DIM  4096
#define OUT_DIM 8192
#define BATCH   4096
#define ROWS    4          // rows staged per block, interleaved per-column (b128 gather)
#define TPB     512
#define CPT     4          // columns per thread per chunk
#define NCHUNK  (OUT_DIM / (TPB * CPT))   // 4

typedef float f32x4 __attribute__((ext_vector_type(4)));

// swizzled LDS byte address of the 4-row group for column c.
// bank-group bits [6:4] ^= bits [9:7]  ->  (c ^ ((c>>3)&7)) << 4
__device__ __forceinline__ uint32_t swz(uint32_t c) {
    return (c ^ ((c >> 3) & 7u)) << 4;
}

// difflogic op-coefficient table: op_i(a,b) = T[i][0] + T[i][1]*a + T[i][2]*b + T[i][3]*ab
__device__ __constant__ float c_T[16][4] = {
    {0.f,  0.f,  0.f,  0.f},
    {0.f,  0.f,  0.f,  1.f},
    {0.f,  1.f,  0.f, -1.f},
    {0.f,  1.f,  0.f,  0.f},
    {0.f,  0.f,  1.f, -1.f},
    {0.f,  0.f,  1.f,  0.f},
    {0.f,  1.f,  1.f, -2.f},
    {0.f,  1.f,  1.f, -1.f},
    {1.f, -1.f, -1.f,  1.f},
    {1.f, -1.f, -1.f,  2.f},
    {1.f,  0.f, -1.f,  0.f},
    {1.f,  0.f, -1.f,  1.f},
    {1.f, -1.f,  0.f,  0.f},
    {1.f, -1.f,  0.f,  1.f},
    {1.f,  0.f,  0.f, -1.f},
    {1.f,  0.f,  0.f,  0.f},
};

__global__ __launch_bounds__(256) void coeff_kernel(const float* __restrict__ w,
                                                    float4* __restrict__ coeff) {
    int j = blockIdx.x * blockDim.x + threadIdx.x;
    if (j >= OUT_DIM) return;
    const float4* wp = (const float4*)(w + (size_t)j * 16);
    float4 a0 = wp[0], a1 = wp[1], a2 = wp[2], a3 = wp[3];
    float v[16] = {a0.x, a0.y, a0.z, a0.w, a1.x, a1.y, a1.z, a1.w,
                   a2.x, a2.y, a2.z, a2.w, a3.x, a3.y, a3.z, a3.w};
    float m = v[0];
#pragma unroll
    for (int i = 1; i < 16; ++i) m = fmaxf(m, v[i]);
    float s = 0.f, c0 = 0.f, c1 = 0.f, c2 = 0.f, c3 = 0.f;
#pragma unroll
    for (int i = 0; i < 16; ++i) {
        float e = __expf(v[i] - m);
        s += e;
        c0 += e * c_T[i][0];
        c1 += e * c_T[i][1];
        c2 += e * c_T[i][2];
        c3 += e * c_T[i][3];
    }
    float inv = 1.f / s;
    coeff[j] = make_float4(c0 * inv, c1 * inv, c2 * inv, c3 * inv);
}

// Each block: 4 rows of x staged in LDS, interleaved per column (xs group for
// col c holds {r0,r1,r2,r3}[c] in 16 B), XOR-swizzled so both the transposing
// staging writes and the b128 gathers are bank-conflict-light.
// One ds_read_b128 per (col, a/b) serves 4 rows. Chunk loop fully unrolled
// with register double-buffer prefetch of next chunk's idx/coeff.
__global__ __launch_bounds__(TPB, 4) void logic_main(const float* __restrict__ x,
                                                     const int* __restrict__ idx,
                                                     const float4* __restrict__ coeff,
                                                     float* __restrict__ out) {
    __shared__ float xs[ROWS * IN_DIM];  // 64 KB, swizzled 4-row column groups

    const int row0 = blockIdx.x * ROWS;
    const int jbase = threadIdx.x * CPT;

    // --- prefetch chunk 0's idx/coeff (overlaps with staging) ---
    int4   i0 = *(const int4*)(idx + jbase);
    int4   i1 = *(const int4*)(idx + OUT_DIM + jbase);
    float4 c0 = coeff[jbase + 0];
    float4 c1 = coeff[jbase + 1];
    float4 c2 = coeff[jbase + 2];
    float4 c3 = coeff[jbase + 3];

    // --- stage 4 rows, transposing to interleaved+swizzled layout ---
    {
        const float4* rp = (const float4*)(x + (size_t)row0 * IN_DIM);
#pragma unroll
        for (int it = 0; it < IN_DIM / 4 / TPB; ++it) {  // 2 iters
            const int t = it * TPB + threadIdx.x;        // col-group (4 cols)
            float4 r0 = rp[t];
            float4 r1 = rp[t + IN_DIM / 4];
            float4 r2 = rp[t + 2 * IN_DIM / 4];
            float4 r3 = rp[t + 3 * IN_DIM / 4];
            const float* p0 = &r0.x; const float* p1 = &r1.x;
            const float* p2 = &r2.x; const float* p3 = &r3.x;
#pragma unroll
            for (int k = 0; k < 4; ++k) {
                f32x4 v; v.x = p0[k]; v.y = p1[k]; v.z = p2[k]; v.w = p3[k];
                *(f32x4*)((char*)xs + swz(4u * t + k)) = v;
            }
        }
    }
    __syncthreads();

#pragma unroll
    for (int chunk = 0; chunk < NCHUNK; ++chunk) {
        const int j = chunk * (TPB * CPT) + jbase;
        const int4   I0 = i0, I1 = i1;
        const float4 C0 = c0, C1 = c1, C2 = c2, C3 = c3;
        if (chunk < NCHUNK - 1) {
            const int jn = j + TPB * CPT;
            i0 = *(const int4*)(idx + jn);
            i1 = *(const int4*)(idx + OUT_DIM + jn);
            c0 = coeff[jn + 0];
            c1 = coeff[jn + 1];
            c2 = coeff[jn + 2];
            c3 = coeff[jn + 3];
        }
        // gathers: one b128 per (col, a/b) serves all 4 rows
        const f32x4 A0 = *(const f32x4*)((const char*)xs + swz(I0.x));
        const f32x4 B0 = *(const f32x4*)((const char*)xs + swz(I1.x));
        const f32x4 A1 = *(const f32x4*)((const char*)xs + swz(I0.y));
        const f32x4 B1 = *(const f32x4*)((const char*)xs + swz(I1.y));
        const f32x4 A2 = *(const f32x4*)((const char*)xs + swz(I0.z));
        const f32x4 B2 = *(const f32x4*)((const char*)xs + swz(I1.z));
        const f32x4 A3 = *(const f32x4*)((const char*)xs + swz(I0.w));
        const f32x4 B3 = *(const f32x4*)((const char*)xs + swz(I1.w));

        f32x4 o0, o1, o2, o3;  // o[r] holds cols j..j+3 for row r
#define POLY(C, a, b) ((C).x + (C).y * (a) + (C).z * (b) + (C).w * ((a) * (b)))
        o0.x = POLY(C0, A0.x, B0.x); o1.x = POLY(C0, A0.y, B0.y);
        o2.x = POLY(C0, A0.z, B0.z); o3.x = POLY(C0, A0.w, B0.w);
        o0.y = POLY(C1, A1.x, B1.x); o1.y = POLY(C1, A1.y, B1.y);
        o2.y = POLY(C1, A1.z, B1.z); o3.y = POLY(C1, A1.w, B1.w);
        o0.z = POLY(C2, A2.x, B2.x); o1.z = POLY(C2, A2.y, B2.y);
        o2.z = POLY(C2, A2.z, B2.z); o3.z = POLY(C2, A2.w, B2.w);
        o0.w = POLY(C3, A3.x, B3.x); o1.w = POLY(C3, A3.y, B3.y);
        o2.w = POLY(C3, A3.z, B3.z); o3.w = POLY(C3, A3.w, B3.w);
#undef POLY

        __builtin_nontemporal_store(o0, (f32x4*)(out + (size_t)(row0 + 0) * OUT_DIM + j));
        __builtin_nontemporal_store(o1, (f32x4*)(out + (size_t)(row0 + 1) * OUT_DIM + j));
        __builtin_nontemporal_store(o2, (f32x4*)(out + (size_t)(row0 + 2) * OUT_DIM + j));
        __builtin_nontemporal_store(o3, (f32x4*)(out + (size_t)(row0 + 3) * OUT_DIM + j));
    }
}

extern "C" void kernel_launch(void* const* d_in, const int* in_sizes, int n_in,
                              void* d_out, int out_size, void* d_ws, size_t ws_size,
                              hipStream_t stream) {
    const float* x   = (const float*)d_in[0];
    const int*   idx = (const int*)d_in[1];     // (2, OUT_DIM) int32
    const float* w   = (const float*)d_in[2];   // (OUT_DIM, 16)
    float* out = (float*)d_out;
    float4* coeff = (float4*)d_ws;              // OUT_DIM float4 = 128 KB scratch

    coeff_kernel<<<OUT_DIM / 256, 256, 0, stream>>>(w, coeff);
    logic_main<<<BATCH / ROWS, TPB, 0, stream>>>(x, idx, coeff, out);
}